// Round 10
// baseline (1341.165 us; speedup 1.0000x reference)
//
#include <hip/hip_runtime.h>
#include <float.h>

// Fused PointNet++ SA module on MI355X (fp32, VALU-bound).
// One block (256 thr) per query. Intermediates in LDS (50.7KB -> 3 blocks/CU).
// Activations stored TRANSPOSED in LDS as [channel][k] so the GEMM inner step
// reads operands as float4 (ds_read_b128). Per c-step: 2x float4 read + 16 FMA.
//
// R5 post-mortem: group_mask (jnp bool) is uploaded by the harness as INT32
// ("integer -> const int*"), not 1-byte bool. Reading it as bytes made only
// k%4==0 neighbors survive the masked max (error signature 3.43 = tail of
// max-of-64 minus max-of-16). Mask is now read as int32/int4. (Robust under
// byte-encoding too for this problem: mask is constant all-ones, and the
// int32 view of all-true bytes is 0x01010101 != 0.)
// R4 post-mortem: W2c overlay raced with h2T writes -> W2 read direct from
// global now. LDS overlay (all simultaneously-live pairs disjoint):
//   h1T [0..4096)      P1 write, P2 read;  W3c [0..4096) in P3 (h1T dead)
//   red [4096..4352)   P3 epilogue (old W1s head, dead after P1)
//   h2T [4352..12544)  P2 write, P3 read (overlays W1s tail/gTf/gTx, dead)
//   W1s [4096..8384)   P0 stage, P1 read
//   gTf [8384..12480)  P0 write, P1 read
//   gTx [12480..12672) P0 write, P1 read
// Total 12672 floats = 50,688 B.

#define KN 64

__device__ __forceinline__ void fma_tile(float (&acc)[4][4], const float4 a, const float4 w) {
    const float av[4] = {a.x, a.y, a.z, a.w};
    const float wv[4] = {w.x, w.y, w.z, w.w};
#pragma unroll
    for (int i = 0; i < 4; ++i)
#pragma unroll
        for (int j = 0; j < 4; ++j)
            acc[i][j] = fmaf(av[i], wv[j], acc[i][j]);
}

__global__ __launch_bounds__(256, 3)
void sa_fused_kernel(const float* __restrict__ xyz,
                     const float* __restrict__ feat,
                     const int* __restrict__ query_idx,
                     const int* __restrict__ group_idx,
                     const int* __restrict__ mask,
                     const float* __restrict__ W1, const float* __restrict__ b1,
                     const float* __restrict__ g1, const float* __restrict__ be1,
                     const float* __restrict__ W2, const float* __restrict__ b2,
                     const float* __restrict__ g2, const float* __restrict__ be2,
                     const float* __restrict__ W3, const float* __restrict__ b3,
                     const float* __restrict__ g3, const float* __restrict__ be3,
                     float* __restrict__ out, int Q)
{
    __shared__ float smem[12672];
    float* h1T = smem;            // [0..4096)
    float* W3c = smem;            // [0..4096)      (P3; h1T dead)
    float* red = smem + 4096;     // [4096..4352)   (P3; W1s head dead)
    float* h2T = smem + 4352;     // [4352..12544)  (P2w/P3r; overlays dead P0/P1 bufs)
    float* W1s = smem + 4096;     // [4096..8384)   (P0/P1)
    float* gTf = smem + 8384;     // [8384..12480)  (P0/P1)
    float* gTx = smem + 12480;    // [12480..12672) (P0/P1)

    const int t = threadIdx.x;
    const int q = blockIdx.x;

    const int qi = query_idx[q];
    const float qx = xyz[qi * 3 + 0];
    const float qy = xyz[qi * 3 + 1];
    const float qz = xyz[qi * 3 + 2];
    if (t < 3) out[q * 3 + t] = (t == 0 ? qx : (t == 1 ? qy : qz));

    // ---- Phase 0: gather neighbors into transposed gTf/gTx; stage W1 ----
    {
        const int k = t >> 2, sub = t & 3;
        const int gi = group_idx[q * KN + k];
        const float4* frow = reinterpret_cast<const float4*>(feat + (size_t)gi * 64);
#pragma unroll
        for (int j = 0; j < 4; ++j) {
            const float4 f = frow[sub * 4 + j];
            const int c = sub * 16 + j * 4;
            gTf[(c + 0) * 64 + k] = f.x;
            gTf[(c + 1) * 64 + k] = f.y;
            gTf[(c + 2) * 64 + k] = f.z;
            gTf[(c + 3) * 64 + k] = f.w;
        }
        if (sub == 0) {
            gTx[0 * 64 + k] = xyz[gi * 3 + 0] - qx;
            gTx[1 * 64 + k] = xyz[gi * 3 + 1] - qy;
            gTx[2 * 64 + k] = xyz[gi * 3 + 2] - qz;
        }
    }
    // Stage W1 (67x64 = 4288 floats = 1072 float4)
    for (int i = t; i < 1072; i += 256)
        reinterpret_cast<float4*>(W1s)[i] = reinterpret_cast<const float4*>(W1)[i];
    __syncthreads();

    const int kt = t >> 4, k0 = kt * 4;   // k-tile  (16 tiles of 4)
    const int dt = t & 15, d0 = dt * 4;   // d-tile  (16 tiles of 4)

    // ---- Phase 1: h1T[d][k] = relu((g^T @ W1)*g1 + b1*g1 + be1), d in [0,64) ----
    {
        float s_[4], bb_[4];
#pragma unroll
        for (int j = 0; j < 4; ++j) {
            s_[j] = g1[d0 + j];
            bb_[j] = fmaf(b1[d0 + j], s_[j], be1[d0 + j]);
        }

        float acc[4][4];
#pragma unroll
        for (int i = 0; i < 4; ++i)
#pragma unroll
            for (int j = 0; j < 4; ++j) acc[i][j] = 0.f;

#pragma unroll
        for (int c = 0; c < 3; ++c) {
            const float4 a = *reinterpret_cast<const float4*>(&gTx[c * 64 + k0]);
            const float4 w = *reinterpret_cast<const float4*>(&W1s[c * 64 + d0]);
            fma_tile(acc, a, w);
        }
#pragma unroll 4
        for (int cf = 0; cf < 64; ++cf) {
            const float4 a = *reinterpret_cast<const float4*>(&gTf[cf * 64 + k0]);
            const float4 w = *reinterpret_cast<const float4*>(&W1s[(3 + cf) * 64 + d0]);
            fma_tile(acc, a, w);
        }
#pragma unroll
        for (int j = 0; j < 4; ++j) {
            float4 o;
            o.x = fmaxf(fmaf(acc[0][j], s_[j], bb_[j]), 0.f);
            o.y = fmaxf(fmaf(acc[1][j], s_[j], bb_[j]), 0.f);
            o.z = fmaxf(fmaf(acc[2][j], s_[j], bb_[j]), 0.f);
            o.w = fmaxf(fmaf(acc[3][j], s_[j], bb_[j]), 0.f);
            *reinterpret_cast<float4*>(&h1T[(d0 + j) * 64 + k0]) = o;
        }
    }
    __syncthreads();   // h1T ready; P0/P1 buffers (W1s/gTf/gTx) now dead

    // ---- Phase 2: h2T[d][k], d in [0,128); W2 read direct from global (L1) ----
    for (int ch = 0; ch < 2; ++ch) {
        float s_[4], bb_[4];
#pragma unroll
        for (int j = 0; j < 4; ++j) {
            const int d = ch * 64 + d0 + j;
            s_[j] = g2[d];
            bb_[j] = fmaf(b2[d], s_[j], be2[d]);
        }

        float acc[4][4];
#pragma unroll
        for (int i = 0; i < 4; ++i)
#pragma unroll
            for (int j = 0; j < 4; ++j) acc[i][j] = 0.f;

#pragma unroll 4
        for (int c = 0; c < 64; ++c) {
            const float4 a = *reinterpret_cast<const float4*>(&h1T[c * 64 + k0]);
            const float4 w = *reinterpret_cast<const float4*>(&W2[c * 128 + ch * 64 + d0]);
            fma_tile(acc, a, w);
        }
#pragma unroll
        for (int j = 0; j < 4; ++j) {
            const int d = ch * 64 + d0 + j;
            float4 o;
            o.x = fmaxf(fmaf(acc[0][j], s_[j], bb_[j]), 0.f);
            o.y = fmaxf(fmaf(acc[1][j], s_[j], bb_[j]), 0.f);
            o.z = fmaxf(fmaf(acc[2][j], s_[j], bb_[j]), 0.f);
            o.w = fmaxf(fmaf(acc[3][j], s_[j], bb_[j]), 0.f);
            *reinterpret_cast<float4*>(&h2T[d * 64 + k0]) = o;
        }
    }
    __syncthreads();   // h2T ready; h1T now dead (W3c may overlay it)

    // ---- Phase 3: h3 + masked max-pool; 4 d-chunks x 2 c-halves of W3 ----
    // group_mask is int32 on device (harness uploads bool as int32).
    const int4 mi = *reinterpret_cast<const int4*>(mask + (size_t)q * KN + k0);

    for (int ch = 0; ch < 4; ++ch) {
        float acc[4][4];
#pragma unroll
        for (int i = 0; i < 4; ++i)
#pragma unroll
            for (int j = 0; j < 4; ++j) acc[i][j] = 0.f;

        for (int ch2 = 0; ch2 < 2; ++ch2) {
            for (int i = t; i < 1024; i += 256) {
                const int c = i >> 4, col = (i & 15) << 2;
                reinterpret_cast<float4*>(W3c)[i] =
                    *reinterpret_cast<const float4*>(&W3[(ch2 * 64 + c) * 256 + ch * 64 + col]);
            }
            __syncthreads();

#pragma unroll 4
            for (int c = 0; c < 64; ++c) {
                const float4 a = *reinterpret_cast<const float4*>(&h2T[(ch2 * 64 + c) * 64 + k0]);
                const float4 w = *reinterpret_cast<const float4*>(&W3c[c * 64 + d0]);
                fma_tile(acc, a, w);
            }
            __syncthreads();
        }

        // Epilogue: affine+relu+mask, per-thread k-max, intra-wave kt reduce.
#pragma unroll
        for (int j = 0; j < 4; ++j) {
            const int d = ch * 64 + d0 + j;
            const float s = g3[d];
            const float bb = fmaf(b3[d], s, be3[d]);
            float v0 = fmaxf(fmaf(acc[0][j], s, bb), 0.f);
            float v1 = fmaxf(fmaf(acc[1][j], s, bb), 0.f);
            float v2 = fmaxf(fmaf(acc[2][j], s, bb), 0.f);
            float v3 = fmaxf(fmaf(acc[3][j], s, bb), 0.f);
            v0 = mi.x ? v0 : -FLT_MAX;   // jnp.where(mask, h, finfo.min)
            v1 = mi.y ? v1 : -FLT_MAX;
            v2 = mi.z ? v2 : -FLT_MAX;
            v3 = mi.w ? v3 : -FLT_MAX;
            float m = fmaxf(fmaxf(v0, v1), fmaxf(v2, v3));
            // reduce over the wave's 4 kt subgroups (lanes l, l^16, l^32 share dt)
            m = fmaxf(m, __shfl_xor(m, 16));
            m = fmaxf(m, __shfl_xor(m, 32));
            if ((t & 63) < 16) red[(t >> 6) * 64 + d0 + j] = m;
        }
        __syncthreads();

        if (t < 64) {
            float m = fmaxf(fmaxf(red[t], red[64 + t]), fmaxf(red[128 + t], red[192 + t]));
            out[(size_t)Q * 3 + (size_t)q * 256 + ch * 64 + t] = m;
        }
        __syncthreads();
    }
}

extern "C" void kernel_launch(void* const* d_in, const int* in_sizes, int n_in,
                              void* d_out, int out_size, void* d_ws, size_t ws_size,
                              hipStream_t stream) {
    const float* xyz        = (const float*)d_in[0];
    const float* feat       = (const float*)d_in[1];
    const int*   query_idx  = (const int*)d_in[2];
    const int*   group_idx  = (const int*)d_in[3];
    const int*   mask       = (const int*)d_in[4];  // bool uploaded as int32
    const float* W1  = (const float*)d_in[5];
    const float* b1  = (const float*)d_in[6];
    const float* g1  = (const float*)d_in[7];
    const float* be1 = (const float*)d_in[8];
    const float* W2  = (const float*)d_in[9];
    const float* b2  = (const float*)d_in[10];
    const float* g2  = (const float*)d_in[11];
    const float* be2 = (const float*)d_in[12];
    const float* W3  = (const float*)d_in[13];
    const float* b3  = (const float*)d_in[14];
    const float* g3  = (const float*)d_in[15];
    const float* be3 = (const float*)d_in[16];
    float* out = (float*)d_out;

    const int Q = in_sizes[2];  // 16384
    sa_fused_kernel<<<Q, 256, 0, stream>>>(xyz, feat, query_idx, group_idx, mask,
                                           W1, b1, g1, be1, W2, b2, g2, be2,
                                           W3, b3, g3, be3, out, Q);
}

// Round 13
// 496.858 us; speedup vs baseline: 2.6993x; 2.6993x over previous
//
#include <hip/hip_runtime.h>
#include <float.h>

// Fused PointNet++ SA module on MI355X — bf16 MFMA version.
// One block (256 thr = 4 waves) per query. Three GEMMs (67->64->128->256 over
// 64 neighbors) on matrix cores, fp32 accumulate, fused affine+ReLU epilogues,
// masked max-pool finale.
//
// R11 post-mortem: P0a zeroed only 832 u32x4 = 6656 ushorts = A1 only; WT1's
// K-pad (c=67..95) kept stale LDS garbage. bf16-NaN garbage patterns there give
// 0*NaN=NaN in the ks=2 MFMA slice -> whole h1 columns NaN -> fmaxf(NaN,0)=0
// silently zeroes them -> finite output-scale error (absmax 2.18). Fix: zero
// the FULL A1+WT1 region (1664 u32x4 = 13312 ushorts = 26624 B).
//
// Layout strategy: MFMA A/B frags both want 8 K-contiguous elems per lane.
//   A (activations) stored [k][c] row-major bf16, stride padded for bank balance.
//   B = W^T stored [d][c] bf16 (transposed at staging: coalesced scalar global
//   reads -> packed LDS writes).
//   frag: lane l -> row (l&15) of 16-row tile, k0 = (l>>4)*8.  D: col=l&15,
//   row=(l>>4)*4+reg (m89-verified).
// K=67 zero-padded to 96 (A1 pad AND WT1 pad zeroed).
// Channel order: cols 0..63 = features, 64..66 = rel-xyz; WT1 rows reordered.
//
// LDS map (ushort units, 27136 total = 54272 B -> 3 blocks/CU):
//   A1  @ 0      [64][104]  P0 write, P1 read
//   WT1 @ 6656   [64][104]  P0 write, P1 read
//   A3  @ 0      [64][136]  P2 epi write, P3 read (overlays A1+WT1, dead)
//   A2  @ 13312  [64][72]   P1 epi write, P2 read
//   WT2 @ 17920  [128][72]  P1 stage (overlaps L1 MFMA), P2 read
//   WT3 @ 17920  [64][136]  P3 stage per 64-d chunk (overlays WT2, dead)

#define KN 64

typedef __attribute__((ext_vector_type(8))) short   bf16x8;
typedef __attribute__((ext_vector_type(4))) float   f32x4;
typedef __attribute__((ext_vector_type(8))) unsigned short u16x8;
typedef __attribute__((ext_vector_type(4))) unsigned short u16x4;
typedef __attribute__((ext_vector_type(4))) unsigned int   u32x4;

__device__ __forceinline__ unsigned short f2bf(float f) {
    union { float f; unsigned u; } v; v.f = f;
    unsigned r = v.u + 0x7FFFu + ((v.u >> 16) & 1u);   // RNE
    return (unsigned short)(r >> 16);
}

__global__ __launch_bounds__(256, 3)
void sa_mfma_kernel(const float* __restrict__ xyz,
                    const float* __restrict__ feat,
                    const int* __restrict__ query_idx,
                    const int* __restrict__ group_idx,
                    const int* __restrict__ mask,
                    const float* __restrict__ W1, const float* __restrict__ b1,
                    const float* __restrict__ g1, const float* __restrict__ be1,
                    const float* __restrict__ W2, const float* __restrict__ b2,
                    const float* __restrict__ g2, const float* __restrict__ be2,
                    const float* __restrict__ W3, const float* __restrict__ b3,
                    const float* __restrict__ g3, const float* __restrict__ be3,
                    float* __restrict__ out, int Q)
{
    __shared__ __align__(16) unsigned short lds[27136];
    unsigned short* A1  = lds;          // [64][104]
    unsigned short* WT1 = lds + 6656;   // [64][104]
    unsigned short* A3  = lds;          // [64][136]
    unsigned short* A2  = lds + 13312;  // [64][72]
    unsigned short* WT2 = lds + 17920;  // [128][72]
    unsigned short* WT3 = lds + 17920;  // [64][136]

    const int t = threadIdx.x;
    const int q = blockIdx.x;
    const int w   = t >> 6;      // wave 0..3
    const int l   = t & 63;      // lane
    const int l15 = l & 15;
    const int lg  = l >> 4;      // 0..3
    const int koff = lg * 8;

    const int qi = query_idx[q];
    const float qx = xyz[qi*3+0], qy = xyz[qi*3+1], qz = xyz[qi*3+2];
    if (t < 3) out[q*3 + t] = (t==0 ? qx : (t==1 ? qy : qz));

    // ---- P0a: zero FULL A1+WT1 region (covers both K-pads) ----
    {
        u32x4 z = {0u,0u,0u,0u};
        u32x4* p = reinterpret_cast<u32x4*>(lds);
        for (int i = t; i < 1664; i += 256) p[i] = z;   // 1664*8 ush = 13312 ush
    }
    __syncthreads();

    // ---- P0b: gather A1 + stage WT1 ----
    {
        const int k = t >> 2, sub = t & 3;
        const int gi = group_idx[q*KN + k];
        const float4* fr = reinterpret_cast<const float4*>(feat + (size_t)gi * 64);
        float4 f0 = fr[sub*4+0], f1 = fr[sub*4+1], f2 = fr[sub*4+2], f3 = fr[sub*4+3];
        u16x8 o0, o1;
        o0[0]=f2bf(f0.x); o0[1]=f2bf(f0.y); o0[2]=f2bf(f0.z); o0[3]=f2bf(f0.w);
        o0[4]=f2bf(f1.x); o0[5]=f2bf(f1.y); o0[6]=f2bf(f1.z); o0[7]=f2bf(f1.w);
        o1[0]=f2bf(f2.x); o1[1]=f2bf(f2.y); o1[2]=f2bf(f2.z); o1[3]=f2bf(f2.w);
        o1[4]=f2bf(f3.x); o1[5]=f2bf(f3.y); o1[6]=f2bf(f3.z); o1[7]=f2bf(f3.w);
        *reinterpret_cast<u16x8*>(&A1[k*104 + sub*16])     = o0;
        *reinterpret_cast<u16x8*>(&A1[k*104 + sub*16 + 8]) = o1;
        if (sub == 0) {
            A1[k*104 + 64] = f2bf(xyz[gi*3+0] - qx);
            A1[k*104 + 65] = f2bf(xyz[gi*3+1] - qy);
            A1[k*104 + 66] = f2bf(xyz[gi*3+2] - qz);
        }
        // WT1[d][ct]: ct 0..63 <- W1 rows 3..66 (features); ct 64..66 <- rows 0..2 (xyz)
        const int d  = t & 63;
        const int cq = t >> 6;
#pragma unroll
        for (int itr = 0; itr < 4; ++itr) {
            const int ct0 = itr*16 + cq*4;
            u16x4 pk;
#pragma unroll
            for (int j = 0; j < 4; ++j)
                pk[j] = f2bf(W1[(ct0 + 3 + j)*64 + d]);   // coalesced across d
            *reinterpret_cast<u16x4*>(&WT1[d*104 + ct0]) = pk;
        }
        if (t < 192) {
            const int c = t >> 6;          // 0..2
            WT1[d*104 + 64 + c] = f2bf(W1[c*64 + d]);
        }
    }
    __syncthreads();

    // ---- P1: stage WT2 (global loads hide under L1 MFMA) ----
    {
        const int dh = t & 127;
        const int ch = t >> 7;             // 0..1
#pragma unroll
        for (int itr = 0; itr < 4; ++itr) {
            const int c0 = itr*16 + ch*8;
            u16x4 pa, pb;
#pragma unroll
            for (int j = 0; j < 4; ++j) pa[j] = f2bf(W2[(c0 + j)*128 + dh]);
#pragma unroll
            for (int j = 0; j < 4; ++j) pb[j] = f2bf(W2[(c0 + 4 + j)*128 + dh]);
            *reinterpret_cast<u16x4*>(&WT2[dh*72 + c0])     = pa;
            *reinterpret_cast<u16x4*>(&WT2[dh*72 + c0 + 4]) = pb;
        }
    }
    // ---- L1 MFMA: wave w -> d cols [16w,16w+16) ----
    {
        f32x4 acc[4];
#pragma unroll
        for (int mt = 0; mt < 4; ++mt) acc[mt] = (f32x4){0.f,0.f,0.f,0.f};
#pragma unroll
        for (int ks = 0; ks < 3; ++ks) {
            bf16x8 b = *reinterpret_cast<const bf16x8*>(&WT1[(w*16 + l15)*104 + ks*32 + koff]);
#pragma unroll
            for (int mt = 0; mt < 4; ++mt) {
                bf16x8 a = *reinterpret_cast<const bf16x8*>(&A1[(mt*16 + l15)*104 + ks*32 + koff]);
                acc[mt] = __builtin_amdgcn_mfma_f32_16x16x32_bf16(a, b, acc[mt], 0, 0, 0);
            }
        }
        const int d = w*16 + l15;
        const float s  = g1[d];
        const float bb = fmaf(b1[d], s, be1[d]);
#pragma unroll
        for (int mt = 0; mt < 4; ++mt)
#pragma unroll
            for (int r = 0; r < 4; ++r) {
                float v = fmaxf(fmaf(acc[mt][r], s, bb), 0.f);
                A2[(mt*16 + lg*4 + r)*72 + d] = f2bf(v);
            }
    }
    __syncthreads();

    // ---- L2 MFMA: wave w -> d cols [32w,32w+32) (2 n-tiles) ----
    {
        f32x4 acc[4][2];
#pragma unroll
        for (int mt = 0; mt < 4; ++mt) {
            acc[mt][0] = (f32x4){0.f,0.f,0.f,0.f};
            acc[mt][1] = (f32x4){0.f,0.f,0.f,0.f};
        }
#pragma unroll
        for (int ks = 0; ks < 2; ++ks) {
            bf16x8 b0 = *reinterpret_cast<const bf16x8*>(&WT2[((2*w+0)*16 + l15)*72 + ks*32 + koff]);
            bf16x8 b1v = *reinterpret_cast<const bf16x8*>(&WT2[((2*w+1)*16 + l15)*72 + ks*32 + koff]);
#pragma unroll
            for (int mt = 0; mt < 4; ++mt) {
                bf16x8 a = *reinterpret_cast<const bf16x8*>(&A2[(mt*16 + l15)*72 + ks*32 + koff]);
                acc[mt][0] = __builtin_amdgcn_mfma_f32_16x16x32_bf16(a, b0,  acc[mt][0], 0, 0, 0);
                acc[mt][1] = __builtin_amdgcn_mfma_f32_16x16x32_bf16(a, b1v, acc[mt][1], 0, 0, 0);
            }
        }
#pragma unroll
        for (int ntl = 0; ntl < 2; ++ntl) {
            const int d = (2*w + ntl)*16 + l15;
            const float s  = g2[d];
            const float bb = fmaf(b2[d], s, be2[d]);
#pragma unroll
            for (int mt = 0; mt < 4; ++mt)
#pragma unroll
                for (int r = 0; r < 4; ++r) {
                    float v = fmaxf(fmaf(acc[mt][ntl][r], s, bb), 0.f);
                    A3[(mt*16 + lg*4 + r)*136 + d] = f2bf(v);
                }
        }
    }
    __syncthreads();

    // ---- L3 + masked max-pool: 4 chunks of 64 d-cols ----
    int ms[16];
#pragma unroll
    for (int mt = 0; mt < 4; ++mt) {
        int4 v = *reinterpret_cast<const int4*>(mask + (size_t)q*KN + mt*16 + lg*4);
        ms[mt*4+0] = v.x; ms[mt*4+1] = v.y; ms[mt*4+2] = v.z; ms[mt*4+3] = v.w;
    }
    for (int dc = 0; dc < 4; ++dc) {
        // stage WT3 chunk: rows dd 0..63 <- W3 cols dc*64+dd, all 128 c
        {
            const int dd = t & 63;
            const int cg = t >> 6;         // 0..3
#pragma unroll
            for (int itr = 0; itr < 8; ++itr) {
                const int c0 = itr*16 + cg*4;
                u16x4 pk;
#pragma unroll
                for (int j = 0; j < 4; ++j)
                    pk[j] = f2bf(W3[(size_t)(c0 + j)*256 + dc*64 + dd]);  // coalesced across dd
                *reinterpret_cast<u16x4*>(&WT3[dd*136 + c0]) = pk;
            }
        }
        __syncthreads();
        f32x4 acc[4];
#pragma unroll
        for (int mt = 0; mt < 4; ++mt) acc[mt] = (f32x4){0.f,0.f,0.f,0.f};
#pragma unroll
        for (int ks = 0; ks < 4; ++ks) {
            bf16x8 b = *reinterpret_cast<const bf16x8*>(&WT3[(w*16 + l15)*136 + ks*32 + koff]);
#pragma unroll
            for (int mt = 0; mt < 4; ++mt) {
                bf16x8 a = *reinterpret_cast<const bf16x8*>(&A3[(mt*16 + l15)*136 + ks*32 + koff]);
                acc[mt] = __builtin_amdgcn_mfma_f32_16x16x32_bf16(a, b, acc[mt], 0, 0, 0);
            }
        }
        const int d = dc*64 + w*16 + l15;
        const float s  = g3[d];
        const float bb = fmaf(b3[d], s, be3[d]);
        float mm = -FLT_MAX;
#pragma unroll
        for (int mt = 0; mt < 4; ++mt)
#pragma unroll
            for (int r = 0; r < 4; ++r) {
                float v = fmaxf(fmaf(acc[mt][r], s, bb), 0.f);
                mm = fmaxf(mm, ms[mt*4+r] ? v : -FLT_MAX);   // jnp.where(mask,...)
            }
        mm = fmaxf(mm, __shfl_xor(mm, 16));
        mm = fmaxf(mm, __shfl_xor(mm, 32));
        if (l < 16) out[(size_t)Q*3 + (size_t)q*256 + d] = mm;
        __syncthreads();   // protect WT3 before next chunk's staging
    }
}

extern "C" void kernel_launch(void* const* d_in, const int* in_sizes, int n_in,
                              void* d_out, int out_size, void* d_ws, size_t ws_size,
                              hipStream_t stream) {
    const float* xyz        = (const float*)d_in[0];
    const float* feat       = (const float*)d_in[1];
    const int*   query_idx  = (const int*)d_in[2];
    const int*   group_idx  = (const int*)d_in[3];
    const int*   mask       = (const int*)d_in[4];  // bool uploaded as int32
    const float* W1  = (const float*)d_in[5];
    const float* b1  = (const float*)d_in[6];
    const float* g1  = (const float*)d_in[7];
    const float* be1 = (const float*)d_in[8];
    const float* W2  = (const float*)d_in[9];
    const float* b2  = (const float*)d_in[10];
    const float* g2  = (const float*)d_in[11];
    const float* be2 = (const float*)d_in[12];
    const float* W3  = (const float*)d_in[13];
    const float* b3  = (const float*)d_in[14];
    const float* g3  = (const float*)d_in[15];
    const float* be3 = (const float*)d_in[16];
    float* out = (float*)d_out;

    const int Q = in_sizes[2];  // 16384
    sa_mfma_kernel<<<Q, 256, 0, stream>>>(xyz, feat, query_idx, group_idx, mask,
                                          W1, b1, g1, be1, W2, b2, g2, be2,
                                          W3, b3, g3, be3, out, Q);
}

// Round 14
// 325.766 us; speedup vs baseline: 4.1170x; 1.5252x over previous
//
#include <hip/hip_runtime.h>
#include <float.h>

// Fused PointNet++ SA module on MI355X — bf16 MFMA v2.
// R13 post-mortem: v1 was staging-bound, not MFMA-bound (MfmaUtil 10%,
// ~177 scalar weight loads + f2bf converts per thread vs 92 MFMAs/lane).
// v2: a prep kernel pre-converts/transposes/pads all weights to bf16 in d_ws
// once per launch; the main kernel loads B-fragments straight from ws
// (16B/lane, L2-resident, zero converts, zero weight-LDS). LDS holds only
// activations (26.6KB -> 6 blocks/CU, was 3).
//
// ws layout (ushort units):
//   WT1b @ 0      [64 d][96 c]   c0..63=W1[3+c][d], c64..66=W1[c-64][d], c67..95=0
//   WT2b @ 6144   [128 d][64 c]  = W2[c][d]
//   WT3b @ 14336  [256 d][128 c] = W3[c][d]     (total 47104 ush = 94208 B)
// LDS (ushort): A1 @0 [64][104] (cols 67..103 zeroed; gather-written);
//   A3 @0 [64][136] overlays A1 after L1; A2 @8704 [64][72]. Total 13312 ush.
// Frags (m89/m97-verified): A/B lane l -> row l&15, k0=(l>>4)*8; D col=l&15,
// row=(l>>4)*4+r.

#define KN 64

typedef __attribute__((ext_vector_type(8))) short   bf16x8;
typedef __attribute__((ext_vector_type(4))) float   f32x4;
typedef __attribute__((ext_vector_type(8))) unsigned short u16x8;
typedef __attribute__((ext_vector_type(4))) unsigned int   u32x4;

__device__ __forceinline__ unsigned short f2bf(float f) {
    union { float f; unsigned u; } v; v.f = f;
    unsigned r = v.u + 0x7FFFu + ((v.u >> 16) & 1u);   // RNE
    return (unsigned short)(r >> 16);
}

// ---- prep: fp32 weights -> transposed/padded bf16 in ws ----
__global__ void prep_weights(const float* __restrict__ W1,
                             const float* __restrict__ W2,
                             const float* __restrict__ W3,
                             unsigned short* __restrict__ ws)
{
    const int i = blockIdx.x * 256 + threadIdx.x;
    if (i >= 47104) return;
    float v;
    if (i < 6144) {                       // WT1b [64][96]
        const int d = i / 96, c = i % 96;
        v = (c < 64) ? W1[(3 + c)*64 + d] : (c < 67 ? W1[(c - 64)*64 + d] : 0.f);
    } else if (i < 14336) {               // WT2b [128][64]
        const int j = i - 6144;
        const int d = j >> 6, c = j & 63;
        v = W2[c*128 + d];
    } else {                              // WT3b [256][128]
        const int j = i - 14336;
        const int d = j >> 7, c = j & 127;
        v = W3[c*256 + d];
    }
    ws[i] = f2bf(v);
}

__global__ __launch_bounds__(256, 6)
void sa_mfma2_kernel(const float* __restrict__ xyz,
                     const float* __restrict__ feat,
                     const int* __restrict__ query_idx,
                     const int* __restrict__ group_idx,
                     const int* __restrict__ mask,
                     const unsigned short* __restrict__ wsb,
                     const float* __restrict__ b1, const float* __restrict__ g1,
                     const float* __restrict__ be1,
                     const float* __restrict__ b2, const float* __restrict__ g2,
                     const float* __restrict__ be2,
                     const float* __restrict__ b3, const float* __restrict__ g3,
                     const float* __restrict__ be3,
                     float* __restrict__ out, int Q)
{
    __shared__ __align__(16) unsigned short lds[13312];
    unsigned short* A1 = lds;           // [64][104], cols>=67 zero
    unsigned short* A3 = lds;           // [64][136], overlays A1 after L1
    unsigned short* A2 = lds + 8704;    // [64][72]

    const unsigned short* WT1b = wsb;           // [64][96]
    const unsigned short* WT2b = wsb + 6144;    // [128][64]
    const unsigned short* WT3b = wsb + 14336;   // [256][128]

    const int t = threadIdx.x;
    const int q = blockIdx.x;
    const int w   = t >> 6;      // wave 0..3
    const int l   = t & 63;
    const int l15 = l & 15;
    const int lg  = l >> 4;
    const int koff = lg * 8;

    const int qi = query_idx[q];
    const float qx = xyz[qi*3+0], qy = xyz[qi*3+1], qz = xyz[qi*3+2];
    if (t < 3) out[q*3 + t] = (t==0 ? qx : (t==1 ? qy : qz));

    // ---- zero A1 (covers K-pad cols 67..103) ----
    {
        u32x4 z = {0u,0u,0u,0u};
        u32x4* p = reinterpret_cast<u32x4*>(lds);
        for (int i = t; i < 832; i += 256) p[i] = z;   // 832*8 ush = 6656 = A1
    }
    __syncthreads();

    // ---- gather A1[k][c]: c0..63 features, 64..66 rel-xyz ----
    {
        const int k = t >> 2, sub = t & 3;
        const int gi = group_idx[q*KN + k];
        const float4* fr = reinterpret_cast<const float4*>(feat + (size_t)gi * 64);
        float4 f0 = fr[sub*4+0], f1 = fr[sub*4+1], f2 = fr[sub*4+2], f3 = fr[sub*4+3];
        u16x8 o0, o1;
        o0[0]=f2bf(f0.x); o0[1]=f2bf(f0.y); o0[2]=f2bf(f0.z); o0[3]=f2bf(f0.w);
        o0[4]=f2bf(f1.x); o0[5]=f2bf(f1.y); o0[6]=f2bf(f1.z); o0[7]=f2bf(f1.w);
        o1[0]=f2bf(f2.x); o1[1]=f2bf(f2.y); o1[2]=f2bf(f2.z); o1[3]=f2bf(f2.w);
        o1[4]=f2bf(f3.x); o1[5]=f2bf(f3.y); o1[6]=f2bf(f3.z); o1[7]=f2bf(f3.w);
        *reinterpret_cast<u16x8*>(&A1[k*104 + sub*16])     = o0;
        *reinterpret_cast<u16x8*>(&A1[k*104 + sub*16 + 8]) = o1;
        if (sub == 0) {
            A1[k*104 + 64] = f2bf(xyz[gi*3+0] - qx);
            A1[k*104 + 65] = f2bf(xyz[gi*3+1] - qy);
            A1[k*104 + 66] = f2bf(xyz[gi*3+2] - qz);
        }
    }
    __syncthreads();

    // ---- L1: wave w -> d [16w,16w+16); B from ws ----
    {
        f32x4 acc[4];
#pragma unroll
        for (int mt = 0; mt < 4; ++mt) acc[mt] = (f32x4){0.f,0.f,0.f,0.f};
#pragma unroll
        for (int ks = 0; ks < 3; ++ks) {
            bf16x8 b = *reinterpret_cast<const bf16x8*>(&WT1b[(w*16 + l15)*96 + ks*32 + koff]);
#pragma unroll
            for (int mt = 0; mt < 4; ++mt) {
                bf16x8 a = *reinterpret_cast<const bf16x8*>(&A1[(mt*16 + l15)*104 + ks*32 + koff]);
                acc[mt] = __builtin_amdgcn_mfma_f32_16x16x32_bf16(a, b, acc[mt], 0, 0, 0);
            }
        }
        const int d = w*16 + l15;
        const float s  = g1[d];
        const float bb = fmaf(b1[d], s, be1[d]);
        __syncthreads();   // A1 reads done before A2 writes? A2 disjoint; but A3 overlays A1 only in L2. (kept: orders epi vs other waves' reads)
#pragma unroll
        for (int mt = 0; mt < 4; ++mt)
#pragma unroll
            for (int r = 0; r < 4; ++r) {
                float v = fmaxf(fmaf(acc[mt][r], s, bb), 0.f);
                A2[(mt*16 + lg*4 + r)*72 + d] = f2bf(v);
            }
    }
    __syncthreads();

    // ---- L2: wave w -> d [32w,32w+32); writes A3 (overlays dead A1) ----
    {
        f32x4 acc[4][2];
#pragma unroll
        for (int mt = 0; mt < 4; ++mt) {
            acc[mt][0] = (f32x4){0.f,0.f,0.f,0.f};
            acc[mt][1] = (f32x4){0.f,0.f,0.f,0.f};
        }
#pragma unroll
        for (int ks = 0; ks < 2; ++ks) {
            bf16x8 b0  = *reinterpret_cast<const bf16x8*>(&WT2b[((2*w+0)*16 + l15)*64 + ks*32 + koff]);
            bf16x8 b1v = *reinterpret_cast<const bf16x8*>(&WT2b[((2*w+1)*16 + l15)*64 + ks*32 + koff]);
#pragma unroll
            for (int mt = 0; mt < 4; ++mt) {
                bf16x8 a = *reinterpret_cast<const bf16x8*>(&A2[(mt*16 + l15)*72 + ks*32 + koff]);
                acc[mt][0] = __builtin_amdgcn_mfma_f32_16x16x32_bf16(a, b0,  acc[mt][0], 0, 0, 0);
                acc[mt][1] = __builtin_amdgcn_mfma_f32_16x16x32_bf16(a, b1v, acc[mt][1], 0, 0, 0);
            }
        }
        __syncthreads();   // all A2 reads complete before A3 (overlay of A1 region) writes race nothing; and before next phase reads
#pragma unroll
        for (int ntl = 0; ntl < 2; ++ntl) {
            const int d = (2*w + ntl)*16 + l15;
            const float s  = g2[d];
            const float bb = fmaf(b2[d], s, be2[d]);
#pragma unroll
            for (int mt = 0; mt < 4; ++mt)
#pragma unroll
                for (int r = 0; r < 4; ++r) {
                    float v = fmaxf(fmaf(acc[mt][ntl][r], s, bb), 0.f);
                    A3[(mt*16 + lg*4 + r)*136 + d] = f2bf(v);
                }
        }
    }
    __syncthreads();

    // ---- L3 + masked max-pool: 4 chunks of 64 d; B from ws ----
    int ms[16];
#pragma unroll
    for (int mt = 0; mt < 4; ++mt) {
        int4 v = *reinterpret_cast<const int4*>(mask + (size_t)q*KN + mt*16 + lg*4);
        ms[mt*4+0] = v.x; ms[mt*4+1] = v.y; ms[mt*4+2] = v.z; ms[mt*4+3] = v.w;
    }
#pragma unroll
    for (int dc = 0; dc < 4; ++dc) {
        f32x4 acc[4];
#pragma unroll
        for (int mt = 0; mt < 4; ++mt) acc[mt] = (f32x4){0.f,0.f,0.f,0.f};
#pragma unroll
        for (int ks = 0; ks < 4; ++ks) {
            bf16x8 b = *reinterpret_cast<const bf16x8*>(&WT3b[(dc*64 + w*16 + l15)*128 + ks*32 + koff]);
#pragma unroll
            for (int mt = 0; mt < 4; ++mt) {
                bf16x8 a = *reinterpret_cast<const bf16x8*>(&A3[(mt*16 + l15)*136 + ks*32 + koff]);
                acc[mt] = __builtin_amdgcn_mfma_f32_16x16x32_bf16(a, b, acc[mt], 0, 0, 0);
            }
        }
        const int d = dc*64 + w*16 + l15;
        const float s  = g3[d];
        const float bb = fmaf(b3[d], s, be3[d]);
        float mm = -FLT_MAX;
#pragma unroll
        for (int mt = 0; mt < 4; ++mt)
#pragma unroll
            for (int r = 0; r < 4; ++r) {
                float v = fmaxf(fmaf(acc[mt][r], s, bb), 0.f);
                mm = fmaxf(mm, ms[mt*4+r] ? v : -FLT_MAX);   // jnp.where(mask,...)
            }
        mm = fmaxf(mm, __shfl_xor(mm, 16));
        mm = fmaxf(mm, __shfl_xor(mm, 32));
        if (l < 16) out[(size_t)Q*3 + (size_t)q*256 + d] = mm;
    }
}

extern "C" void kernel_launch(void* const* d_in, const int* in_sizes, int n_in,
                              void* d_out, int out_size, void* d_ws, size_t ws_size,
                              hipStream_t stream) {
    const float* xyz        = (const float*)d_in[0];
    const float* feat       = (const float*)d_in[1];
    const int*   query_idx  = (const int*)d_in[2];
    const int*   group_idx  = (const int*)d_in[3];
    const int*   mask       = (const int*)d_in[4];  // bool uploaded as int32
    const float* W1  = (const float*)d_in[5];
    const float* b1  = (const float*)d_in[6];
    const float* g1  = (const float*)d_in[7];
    const float* be1 = (const float*)d_in[8];
    const float* W2  = (const float*)d_in[9];
    const float* b2  = (const float*)d_in[10];
    const float* g2  = (const float*)d_in[11];
    const float* be2 = (const float*)d_in[12];
    const float* W3  = (const float*)d_in[13];
    const float* b3  = (const float*)d_in[14];
    const float* g3  = (const float*)d_in[15];
    const float* be3 = (const float*)d_in[16];
    float* out = (float*)d_out;
    unsigned short* wsb = (unsigned short*)d_ws;

    const int Q = in_sizes[2];  // 16384
    prep_weights<<<184, 256, 0, stream>>>(W1, W2, W3, wsb);
    sa_mfma2_kernel<<<Q, 256, 0, stream>>>(xyz, feat, query_idx, group_idx, mask,
                                           wsb, b1, g1, be1, b2, g2, be2,
                                           b3, g3, be3, out, Q);
}